// Round 10
// baseline (218.602 us; speedup 1.0000x reference)
//
#include <hip/hip_runtime.h>

// entmax-1.5 attention: B=8,H=8,S=1024,D=64, fp32 in/out.
// Prepass (merged): K -> bf16 ws; V -> bf16 transposed [bh][d][s] ws.
// Main: 16 q-rows/block. NO K/V LDS staging at all — each lane loads its
// own MFMA B-fragments (16 B short8) straight from global into VGPRs with
// a 1-tile-ahead register double-buffer (there is zero cross-wave tile
// reuse in this layout, so LDS staging was pure overhead; also avoids the
// gfx950 hazard where vmcnt(0)-gated same-wave consumption of
// global_load_lds data without s_barrier reads stale LDS — rounds 8/9).
// LDS = sP only (33 KB) -> 4 blocks/CU. 2 block barriers (around entmax).

#define S_LEN 1024
#define D_DIM 64
#define TQ    16
#define TK    64
#define NT    (S_LEN / TK)    // 16 tiles
#define PPAD  1032            // sP row stride (bf16 elems)

typedef short  short8   __attribute__((ext_vector_type(8)));
typedef float  f32x4    __attribute__((ext_vector_type(4)));
typedef float  f32x2    __attribute__((ext_vector_type(2)));
typedef unsigned short ushort8v __attribute__((ext_vector_type(8)));

static __device__ __forceinline__ unsigned short f2bf(float f) {
    unsigned u = __builtin_bit_cast(unsigned, f);
    u += 0x7FFFu + ((u >> 16) & 1u);           // RNE
    return (unsigned short)(u >> 16);
}
static __device__ __forceinline__ float bf_lo(unsigned u) {
    return __builtin_bit_cast(float, u << 16);
}
static __device__ __forceinline__ float bf_hi(unsigned u) {
    return __builtin_bit_cast(float, u & 0xFFFF0000u);
}

// ---------- merged prepass: per block one (bh, s-tile): K convert + V transpose ----------
__global__ __launch_bounds__(256) void prep_kv(
    const float* __restrict__ K, const float* __restrict__ V,
    unsigned short* __restrict__ Kbf, unsigned short* __restrict__ Vt)
{
    __shared__ float t[D_DIM * 65];
    const int tid = threadIdx.x;
    const int bh = blockIdx.x >> 4;
    const int s0 = (blockIdx.x & 15) * 64;

    // --- issue ALL global loads up front (MLP) ---
    const float* Kb = K + ((size_t)bh * S_LEN + s0) * D_DIM;
    const int kr = tid >> 2, kc = (tid & 3) * 16;
    float4 k0 = *(const float4*)(Kb + kr * D_DIM + kc);
    float4 k1 = *(const float4*)(Kb + kr * D_DIM + kc + 4);
    float4 k2 = *(const float4*)(Kb + kr * D_DIM + kc + 8);
    float4 k3 = *(const float4*)(Kb + kr * D_DIM + kc + 12);

    const float* Vb = V + ((size_t)bh * S_LEN + s0) * D_DIM;
    const int sr = tid >> 4, d4 = (tid & 15) * 4;
    float4 v0 = *(const float4*)(Vb + (sr +  0) * D_DIM + d4);
    float4 v1 = *(const float4*)(Vb + (sr + 16) * D_DIM + d4);
    float4 v2 = *(const float4*)(Vb + (sr + 32) * D_DIM + d4);
    float4 v3 = *(const float4*)(Vb + (sr + 48) * D_DIM + d4);

    // --- V -> LDS (transpose staging) ---
    {
        const float4 vv[4] = {v0, v1, v2, v3};
        #pragma unroll
        for (int ii = 0; ii < 4; ++ii) {
            const int s = sr + 16 * ii;
            t[(d4+0)*65 + s] = vv[ii].x; t[(d4+1)*65 + s] = vv[ii].y;
            t[(d4+2)*65 + s] = vv[ii].z; t[(d4+3)*65 + s] = vv[ii].w;
        }
    }

    // --- K convert + store (independent of LDS) ---
    {
        ushort8v a, b;
        a[0]=f2bf(k0.x); a[1]=f2bf(k0.y); a[2]=f2bf(k0.z); a[3]=f2bf(k0.w);
        a[4]=f2bf(k1.x); a[5]=f2bf(k1.y); a[6]=f2bf(k1.z); a[7]=f2bf(k1.w);
        b[0]=f2bf(k2.x); b[1]=f2bf(k2.y); b[2]=f2bf(k2.z); b[3]=f2bf(k2.w);
        b[4]=f2bf(k3.x); b[5]=f2bf(k3.y); b[6]=f2bf(k3.z); b[7]=f2bf(k3.w);
        unsigned short* kout = Kbf + ((size_t)bh * S_LEN + s0 + kr) * D_DIM + kc;
        *(ushort8v*)(kout)     = a;
        *(ushort8v*)(kout + 8) = b;
    }
    __syncthreads();

    // --- V transpose out of LDS ---
    {
        const int d = tid >> 2, sq = tid & 3;
        ushort8v o0, o1;
        #pragma unroll
        for (int j = 0; j < 8; ++j) {
            o0[j] = f2bf(t[d*65 + sq*16 + j]);
            o1[j] = f2bf(t[d*65 + sq*16 + 8 + j]);
        }
        unsigned short* outp = Vt + ((size_t)bh * D_DIM + d) * S_LEN + s0 + sq * 16;
        *(ushort8v*)(outp)     = o0;
        *(ushort8v*)(outp + 8) = o1;
    }
}

// ---------- main ----------
__global__ __launch_bounds__(256, 4) void entmax_attn_mfma(
    const float* __restrict__ Q, const unsigned short* __restrict__ Kbf,
    const unsigned short* __restrict__ Vt, float* __restrict__ O)
{
#pragma clang fp contract(fast)
    __shared__ __align__(16) unsigned short sP[TQ * PPAD];   // 33024 B
    __shared__ float sInv[TQ];

    const int tid  = threadIdx.x;
    const int lane = tid & 63;
    const int wave = tid >> 6;
    const int quad = lane >> 4;
    const int l15  = lane & 15;

    // XCD swizzle: pin each bh's 64 blocks to one XCD (blockIdx%8 = XCD).
    const int xcd = blockIdx.x & 7;
    const int kk  = blockIdx.x >> 3;
    const int bh  = (xcd << 3) | (kk >> 6);
    const int qt  = kk & 63;

    const float* Qb = Q + ((size_t)bh * S_LEN + qt * TQ) * D_DIM;
    const unsigned short* Kb = Kbf + (size_t)bh * S_LEN * D_DIM;
    const unsigned short* Vb = Vt  + (size_t)bh * D_DIM * S_LEN;

    // per-lane fragment sources (row = wave*16+l15 for both K and V^T)
    const unsigned short* kfrag = Kb + (size_t)(wave * 16 + l15) * D_DIM + quad * 8;
    const unsigned short* vfrag = Vb + (size_t)(wave * 16 + l15) * S_LEN + quad * 8;

    // ---- issue K tile-0 fragments + Q fragments up front (MLP) ----
    short8 kb0 = *(const short8*)(kfrag);
    short8 kb1 = *(const short8*)(kfrag + 32);
    const float* qrow = Qb + l15 * D_DIM + quad * 8;
    float4 q0 = *(const float4*)(qrow);
    float4 q1 = *(const float4*)(qrow + 4);
    float4 q2 = *(const float4*)(qrow + 32);
    float4 q3 = *(const float4*)(qrow + 36);

    // A-fragments: A[m=l15][k=quad*8+j], scale 1/16 folded (exact)
    short8 a0, a1;
    a0[0]=(short)f2bf(q0.x*0.0625f); a0[1]=(short)f2bf(q0.y*0.0625f);
    a0[2]=(short)f2bf(q0.z*0.0625f); a0[3]=(short)f2bf(q0.w*0.0625f);
    a0[4]=(short)f2bf(q1.x*0.0625f); a0[5]=(short)f2bf(q1.y*0.0625f);
    a0[6]=(short)f2bf(q1.z*0.0625f); a0[7]=(short)f2bf(q1.w*0.0625f);
    a1[0]=(short)f2bf(q2.x*0.0625f); a1[1]=(short)f2bf(q2.y*0.0625f);
    a1[2]=(short)f2bf(q2.z*0.0625f); a1[3]=(short)f2bf(q2.w*0.0625f);
    a1[4]=(short)f2bf(q3.x*0.0625f); a1[5]=(short)f2bf(q3.y*0.0625f);
    a1[6]=(short)f2bf(q3.z*0.0625f); a1[7]=(short)f2bf(q3.w*0.0625f);

    // ===== GEMM1: scores = (Q/16).K^T — register double-buffered fragments ====
    #pragma unroll 2
    for (int kt = 0; kt < NT; ++kt) {
        short8 nb0, nb1;
        if (kt < NT - 1) {
            const unsigned short* nf = kfrag + (size_t)(kt + 1) * TK * D_DIM;
            nb0 = *(const short8*)(nf);
            nb1 = *(const short8*)(nf + 32);
        }
        f32x4 acc = {0.f, 0.f, 0.f, 0.f};
        acc = __builtin_amdgcn_mfma_f32_16x16x32_bf16(a0, kb0, acc, 0, 0, 0);
        acc = __builtin_amdgcn_mfma_f32_16x16x32_bf16(a1, kb1, acc, 0, 0, 0);
        const int col = kt * TK + wave * 16 + l15;
        #pragma unroll
        for (int i = 0; i < 4; ++i)        // C: col=l15-derived, row=quad*4+i
            sP[(quad * 4 + i) * PPAD + col] = f2bf(acc[i]);
        kb0 = nb0; kb1 = nb1;
    }
    __syncthreads();                       // sP complete (cross-wave)

    // V tile-0 fragments: issued here, fly under the whole entmax phase
    short8 vb0 = *(const short8*)(vfrag);
    short8 vb1 = *(const short8*)(vfrag + 32);

    // ========== entmax-1.5: row = wave*4+quad, packed-f32, reg-pinned ==========
    {
        const int myrow = wave * 4 + quad;
        unsigned short* prow = &sP[myrow * PPAD];
        f32x2 xp[32];
        #pragma unroll
        for (int i = 0; i < 8; ++i) {
            uint4 c4 = *(const uint4*)(prow + (i * 16 + l15) * 8);
            xp[i*4+0] = (f32x2){bf_lo(c4.x), bf_hi(c4.x)};
            xp[i*4+1] = (f32x2){bf_lo(c4.y), bf_hi(c4.y)};
            xp[i*4+2] = (f32x2){bf_lo(c4.z), bf_hi(c4.z)};
            xp[i*4+3] = (f32x2){bf_lo(c4.w), bf_hi(c4.w)};
        }
        // pin score array (defeat rematerialization)
        #pragma unroll
        for (int j = 0; j < 32; ++j) {
            double d = __builtin_bit_cast(double, xp[j]);
            asm volatile("" : "+v"(d));
            xp[j] = __builtin_bit_cast(f32x2, d);
        }

        f32x2 mm = xp[0];
        #pragma unroll
        for (int j = 1; j < 32; ++j) mm = __builtin_elementwise_max(mm, xp[j]);
        float m = fmaxf(mm[0], mm[1]);
        #pragma unroll
        for (int off = 1; off < 16; off <<= 1) m = fmaxf(m, __shfl_xor(m, off));

        // Newton from below on convex decreasing g(tau)=sum (x-tau)+^2;
        // raw coordinates: root in [m-1, m), g(m-1) >= 1, monotone from below.
        const f32x2 z2 = {0.f, 0.f};
        float tau = m - 1.0f;
        #pragma unroll 1
        for (int it = 0; it < 8; ++it) {
            f32x2 g2 = z2, h2 = z2;
            const f32x2 t2 = {tau, tau};
            #pragma unroll
            for (int j = 0; j < 32; ++j) {
                f32x2 t = __builtin_elementwise_max(xp[j] - t2, z2);
                g2 = t * t + g2;               // contracts to v_pk_fma_f32
                h2 = h2 + t;
            }
            float g = g2[0] + g2[1], h = h2[0] + h2[1];
            #pragma unroll
            for (int off = 1; off < 16; off <<= 1) {
                g += __shfl_xor(g, off);
                h += __shfl_xor(h, off);
            }
            tau += (g - 1.0f) * __builtin_amdgcn_rcpf(h + h);
        }

        // p = (x - tau)+^2 -> bf16, b128 stores, accumulate sum of rounded p
        float ps = 0.f;
        const f32x2 tv = {tau, tau};
        #pragma unroll
        for (int i = 0; i < 8; ++i) {
            unsigned pk[4];
            #pragma unroll
            for (int w = 0; w < 4; ++w) {
                f32x2 t = __builtin_elementwise_max(xp[i*4+w] - tv, z2);
                f32x2 p = t * t;
                unsigned b0 = f2bf(p[0]), b1 = f2bf(p[1]);
                ps += bf_lo(b0) + bf_lo(b1);
                pk[w] = b0 | (b1 << 16);
            }
            uint4 o; o.x = pk[0]; o.y = pk[1]; o.z = pk[2]; o.w = pk[3];
            *(uint4*)(prow + (i * 16 + l15) * 8) = o;
        }
        #pragma unroll
        for (int off = 1; off < 16; off <<= 1) ps += __shfl_xor(ps, off);
        if (l15 == 0) sInv[myrow] = 1.0f / ps;
    }
    __syncthreads();                       // p-values complete (cross-wave)

    // ===== GEMM2: O = P . V — register double-buffered V^T fragments =====
    f32x4 oacc = {0.f, 0.f, 0.f, 0.f};
    #pragma unroll 2
    for (int kt = 0; kt < NT; ++kt) {
        short8 nv0, nv1;
        if (kt < NT - 1) {
            const unsigned short* nf = vfrag + (kt + 1) * TK;
            nv0 = *(const short8*)(nf);
            nv1 = *(const short8*)(nf + 32);
        }
        short8 pa0 = *(const short8*)(&sP[l15 * PPAD + kt * TK + quad * 8]);
        short8 pa1 = *(const short8*)(&sP[l15 * PPAD + kt * TK + 32 + quad * 8]);
        oacc = __builtin_amdgcn_mfma_f32_16x16x32_bf16(pa0, vb0, oacc, 0, 0, 0);
        oacc = __builtin_amdgcn_mfma_f32_16x16x32_bf16(pa1, vb1, oacc, 0, 0, 0);
        vb0 = nv0; vb1 = nv1;
    }

    // ---- epilogue: renormalize + store ----
    float* Ob = O + ((size_t)bh * S_LEN + qt * TQ) * D_DIM;
    const int n0 = wave * 16;
    #pragma unroll
    for (int i = 0; i < 4; ++i) {
        const int row = quad * 4 + i;
        Ob[row * D_DIM + n0 + l15] = oacc[i] * sInv[row];
    }
}

extern "C" void kernel_launch(void* const* d_in, const int* in_sizes, int n_in,
                              void* d_out, int out_size, void* d_ws, size_t ws_size,
                              hipStream_t stream) {
    const float* q = (const float*)d_in[0];
    const float* k = (const float*)d_in[1];
    const float* v = (const float*)d_in[2];
    float* o = (float*)d_out;

    unsigned short* kbf = (unsigned short*)d_ws;                    // 8 MB
    unsigned short* vt  = kbf + (size_t)64 * S_LEN * D_DIM;         // 8 MB

    // merged prepass: 64 bh x 16 s-tiles, K convert + V transpose per block
    prep_kv<<<1024, 256, 0, stream>>>(k, v, kbf, vt);
    // main: 64 bh x 64 q-tiles, XCD-swizzled
    entmax_attn_mfma<<<4096, 256, 0, stream>>>(q, kbf, vt, o);
}

// Round 11
// 215.397 us; speedup vs baseline: 1.0149x; 1.0149x over previous
//
#include <hip/hip_runtime.h>

// entmax-1.5 attention: B=8,H=8,S=1024,D=64, fp32 in/out.
// Prepass (merged): K -> bf16 ws; V -> bf16 transposed [bh][d][s] ws.
// Main: 16 q-rows/block. No K/V LDS staging — each lane loads its own MFMA
// B-fragments (16 B short8) straight from global into VGPRs with a
// 4-TILE-DEEP register ring (round 10's 1-deep buffer exposed ~150 cyc of
// L2 latency per iteration; depth 4 x ~50 cyc compute covers ~200 cyc).
// LDS = sP only (33 KB) -> 4 blocks/CU. 2 block barriers (around entmax).

#define S_LEN 1024
#define D_DIM 64
#define TQ    16
#define TK    64
#define NT    (S_LEN / TK)    // 16 tiles
#define PPAD  1032            // sP row stride (bf16 elems)

typedef short  short8   __attribute__((ext_vector_type(8)));
typedef float  f32x4    __attribute__((ext_vector_type(4)));
typedef float  f32x2    __attribute__((ext_vector_type(2)));
typedef unsigned short ushort8v __attribute__((ext_vector_type(8)));

static __device__ __forceinline__ unsigned short f2bf(float f) {
    unsigned u = __builtin_bit_cast(unsigned, f);
    u += 0x7FFFu + ((u >> 16) & 1u);           // RNE
    return (unsigned short)(u >> 16);
}
static __device__ __forceinline__ float bf_lo(unsigned u) {
    return __builtin_bit_cast(float, u << 16);
}
static __device__ __forceinline__ float bf_hi(unsigned u) {
    return __builtin_bit_cast(float, u & 0xFFFF0000u);
}

// ---------- merged prepass: per block one (bh, s-tile): K convert + V transpose ----------
__global__ __launch_bounds__(256) void prep_kv(
    const float* __restrict__ K, const float* __restrict__ V,
    unsigned short* __restrict__ Kbf, unsigned short* __restrict__ Vt)
{
    __shared__ float t[D_DIM * 65];
    const int tid = threadIdx.x;
    const int bh = blockIdx.x >> 4;
    const int s0 = (blockIdx.x & 15) * 64;

    // --- issue ALL global loads up front (MLP) ---
    const float* Kb = K + ((size_t)bh * S_LEN + s0) * D_DIM;
    const int kr = tid >> 2, kc = (tid & 3) * 16;
    float4 k0 = *(const float4*)(Kb + kr * D_DIM + kc);
    float4 k1 = *(const float4*)(Kb + kr * D_DIM + kc + 4);
    float4 k2 = *(const float4*)(Kb + kr * D_DIM + kc + 8);
    float4 k3 = *(const float4*)(Kb + kr * D_DIM + kc + 12);

    const float* Vb = V + ((size_t)bh * S_LEN + s0) * D_DIM;
    const int sr = tid >> 4, d4 = (tid & 15) * 4;
    float4 v0 = *(const float4*)(Vb + (sr +  0) * D_DIM + d4);
    float4 v1 = *(const float4*)(Vb + (sr + 16) * D_DIM + d4);
    float4 v2 = *(const float4*)(Vb + (sr + 32) * D_DIM + d4);
    float4 v3 = *(const float4*)(Vb + (sr + 48) * D_DIM + d4);

    // --- V -> LDS (transpose staging) ---
    {
        const float4 vv[4] = {v0, v1, v2, v3};
        #pragma unroll
        for (int ii = 0; ii < 4; ++ii) {
            const int s = sr + 16 * ii;
            t[(d4+0)*65 + s] = vv[ii].x; t[(d4+1)*65 + s] = vv[ii].y;
            t[(d4+2)*65 + s] = vv[ii].z; t[(d4+3)*65 + s] = vv[ii].w;
        }
    }

    // --- K convert + store (independent of LDS) ---
    {
        ushort8v a, b;
        a[0]=f2bf(k0.x); a[1]=f2bf(k0.y); a[2]=f2bf(k0.z); a[3]=f2bf(k0.w);
        a[4]=f2bf(k1.x); a[5]=f2bf(k1.y); a[6]=f2bf(k1.z); a[7]=f2bf(k1.w);
        b[0]=f2bf(k2.x); b[1]=f2bf(k2.y); b[2]=f2bf(k2.z); b[3]=f2bf(k2.w);
        b[4]=f2bf(k3.x); b[5]=f2bf(k3.y); b[6]=f2bf(k3.z); b[7]=f2bf(k3.w);
        unsigned short* kout = Kbf + ((size_t)bh * S_LEN + s0 + kr) * D_DIM + kc;
        *(ushort8v*)(kout)     = a;
        *(ushort8v*)(kout + 8) = b;
    }
    __syncthreads();

    // --- V transpose out of LDS ---
    {
        const int d = tid >> 2, sq = tid & 3;
        ushort8v o0, o1;
        #pragma unroll
        for (int j = 0; j < 8; ++j) {
            o0[j] = f2bf(t[d*65 + sq*16 + j]);
            o1[j] = f2bf(t[d*65 + sq*16 + 8 + j]);
        }
        unsigned short* outp = Vt + ((size_t)bh * D_DIM + d) * S_LEN + s0 + sq * 16;
        *(ushort8v*)(outp)     = o0;
        *(ushort8v*)(outp + 8) = o1;
    }
}

// ---------- main ----------
__global__ __launch_bounds__(256, 4) void entmax_attn_mfma(
    const float* __restrict__ Q, const unsigned short* __restrict__ Kbf,
    const unsigned short* __restrict__ Vt, float* __restrict__ O)
{
#pragma clang fp contract(fast)
    __shared__ __align__(16) unsigned short sP[TQ * PPAD];   // 33024 B
    __shared__ float sInv[TQ];

    const int tid  = threadIdx.x;
    const int lane = tid & 63;
    const int wave = tid >> 6;
    const int quad = lane >> 4;
    const int l15  = lane & 15;

    // XCD swizzle: pin each bh's 64 blocks to one XCD (blockIdx%8 = XCD).
    const int xcd = blockIdx.x & 7;
    const int kk  = blockIdx.x >> 3;
    const int bh  = (xcd << 3) | (kk >> 6);
    const int qt  = kk & 63;

    const float* Qb = Q + ((size_t)bh * S_LEN + qt * TQ) * D_DIM;
    const unsigned short* Kb = Kbf + (size_t)bh * S_LEN * D_DIM;
    const unsigned short* Vb = Vt  + (size_t)bh * D_DIM * S_LEN;

    // per-lane fragment sources (row = wave*16+l15 for both K and V^T)
    const unsigned short* kfrag = Kb + (size_t)(wave * 16 + l15) * D_DIM + quad * 8;
    const unsigned short* vfrag = Vb + (size_t)(wave * 16 + l15) * S_LEN + quad * 8;

    // ---- preload K tiles 0..2 (ring depth 4) + Q fragments up front ----
    short8 kbuf[4][2];
    #pragma unroll
    for (int p = 0; p < 3; ++p) {
        const unsigned short* nf = kfrag + (size_t)p * TK * D_DIM;
        kbuf[p][0] = *(const short8*)(nf);
        kbuf[p][1] = *(const short8*)(nf + 32);
    }
    const float* qrow = Qb + l15 * D_DIM + quad * 8;
    float4 q0 = *(const float4*)(qrow);
    float4 q1 = *(const float4*)(qrow + 4);
    float4 q2 = *(const float4*)(qrow + 32);
    float4 q3 = *(const float4*)(qrow + 36);

    // A-fragments: A[m=l15][k=quad*8+j], scale 1/16 folded (exact)
    short8 a0, a1;
    a0[0]=(short)f2bf(q0.x*0.0625f); a0[1]=(short)f2bf(q0.y*0.0625f);
    a0[2]=(short)f2bf(q0.z*0.0625f); a0[3]=(short)f2bf(q0.w*0.0625f);
    a0[4]=(short)f2bf(q1.x*0.0625f); a0[5]=(short)f2bf(q1.y*0.0625f);
    a0[6]=(short)f2bf(q1.z*0.0625f); a0[7]=(short)f2bf(q1.w*0.0625f);
    a1[0]=(short)f2bf(q2.x*0.0625f); a1[1]=(short)f2bf(q2.y*0.0625f);
    a1[2]=(short)f2bf(q2.z*0.0625f); a1[3]=(short)f2bf(q2.w*0.0625f);
    a1[4]=(short)f2bf(q3.x*0.0625f); a1[5]=(short)f2bf(q3.y*0.0625f);
    a1[6]=(short)f2bf(q3.z*0.0625f); a1[7]=(short)f2bf(q3.w*0.0625f);

    // ===== GEMM1: scores = (Q/16).K^T — 4-deep register ring =====
    #pragma unroll 4
    for (int kt = 0; kt < NT; ++kt) {
        if (kt + 3 < NT) {
            const unsigned short* nf = kfrag + (size_t)(kt + 3) * TK * D_DIM;
            kbuf[(kt + 3) & 3][0] = *(const short8*)(nf);
            kbuf[(kt + 3) & 3][1] = *(const short8*)(nf + 32);
        }
        f32x4 acc = {0.f, 0.f, 0.f, 0.f};
        acc = __builtin_amdgcn_mfma_f32_16x16x32_bf16(a0, kbuf[kt & 3][0], acc, 0, 0, 0);
        acc = __builtin_amdgcn_mfma_f32_16x16x32_bf16(a1, kbuf[kt & 3][1], acc, 0, 0, 0);
        const int col = kt * TK + wave * 16 + l15;
        #pragma unroll
        for (int i = 0; i < 4; ++i)        // C: col=l15-derived, row=quad*4+i
            sP[(quad * 4 + i) * PPAD + col] = f2bf(acc[i]);
    }
    __syncthreads();                       // sP complete (cross-wave)

    // V tile-0 fragments: issued here, fly under the whole entmax phase
    // (only 1 tile pre-entmax to keep register pressure low while xp[] lives)
    short8 vbuf[4][2];
    vbuf[0][0] = *(const short8*)(vfrag);
    vbuf[0][1] = *(const short8*)(vfrag + 32);

    // ========== entmax-1.5: row = wave*4+quad, packed-f32, reg-pinned ==========
    {
        const int myrow = wave * 4 + quad;
        unsigned short* prow = &sP[myrow * PPAD];
        f32x2 xp[32];
        #pragma unroll
        for (int i = 0; i < 8; ++i) {
            uint4 c4 = *(const uint4*)(prow + (i * 16 + l15) * 8);
            xp[i*4+0] = (f32x2){bf_lo(c4.x), bf_hi(c4.x)};
            xp[i*4+1] = (f32x2){bf_lo(c4.y), bf_hi(c4.y)};
            xp[i*4+2] = (f32x2){bf_lo(c4.z), bf_hi(c4.z)};
            xp[i*4+3] = (f32x2){bf_lo(c4.w), bf_hi(c4.w)};
        }
        // pin score array (defeat rematerialization)
        #pragma unroll
        for (int j = 0; j < 32; ++j) {
            double d = __builtin_bit_cast(double, xp[j]);
            asm volatile("" : "+v"(d));
            xp[j] = __builtin_bit_cast(f32x2, d);
        }

        f32x2 mm = xp[0];
        #pragma unroll
        for (int j = 1; j < 32; ++j) mm = __builtin_elementwise_max(mm, xp[j]);
        float m = fmaxf(mm[0], mm[1]);
        #pragma unroll
        for (int off = 1; off < 16; off <<= 1) m = fmaxf(m, __shfl_xor(m, off));

        // Newton from below on convex decreasing g(tau)=sum (x-tau)+^2;
        // raw coordinates: root in [m-1, m), g(m-1) >= 1, monotone from below.
        const f32x2 z2 = {0.f, 0.f};
        float tau = m - 1.0f;
        #pragma unroll 1
        for (int it = 0; it < 8; ++it) {
            f32x2 g2 = z2, h2 = z2;
            const f32x2 t2 = {tau, tau};
            #pragma unroll
            for (int j = 0; j < 32; ++j) {
                f32x2 t = __builtin_elementwise_max(xp[j] - t2, z2);
                g2 = t * t + g2;               // contracts to v_pk_fma_f32
                h2 = h2 + t;
            }
            float g = g2[0] + g2[1], h = h2[0] + h2[1];
            #pragma unroll
            for (int off = 1; off < 16; off <<= 1) {
                g += __shfl_xor(g, off);
                h += __shfl_xor(h, off);
            }
            tau += (g - 1.0f) * __builtin_amdgcn_rcpf(h + h);
        }

        // p = (x - tau)+^2 -> bf16, b128 stores, accumulate sum of rounded p
        float ps = 0.f;
        const f32x2 tv = {tau, tau};
        #pragma unroll
        for (int i = 0; i < 8; ++i) {
            unsigned pk[4];
            #pragma unroll
            for (int w = 0; w < 4; ++w) {
                f32x2 t = __builtin_elementwise_max(xp[i*4+w] - tv, z2);
                f32x2 p = t * t;
                unsigned b0 = f2bf(p[0]), b1 = f2bf(p[1]);
                ps += bf_lo(b0) + bf_lo(b1);
                pk[w] = b0 | (b1 << 16);
            }
            uint4 o; o.x = pk[0]; o.y = pk[1]; o.z = pk[2]; o.w = pk[3];
            *(uint4*)(prow + (i * 16 + l15) * 8) = o;
        }
        #pragma unroll
        for (int off = 1; off < 16; off <<= 1) ps += __shfl_xor(ps, off);
        if (l15 == 0) sInv[myrow] = 1.0f / ps;
    }
    __syncthreads();                       // p-values complete (cross-wave)

    // fill the V ring: tiles 1,2 issued now (tile 0 already landed under entmax)
    #pragma unroll
    for (int p = 1; p < 3; ++p) {
        const unsigned short* nf = vfrag + (size_t)p * TK;
        vbuf[p][0] = *(const short8*)(nf);
        vbuf[p][1] = *(const short8*)(nf + 32);
    }

    // ===== GEMM2: O = P . V — 4-deep register ring =====
    f32x4 oacc = {0.f, 0.f, 0.f, 0.f};
    #pragma unroll 4
    for (int kt = 0; kt < NT; ++kt) {
        if (kt + 3 < NT) {
            const unsigned short* nf = vfrag + (size_t)(kt + 3) * TK;
            vbuf[(kt + 3) & 3][0] = *(const short8*)(nf);
            vbuf[(kt + 3) & 3][1] = *(const short8*)(nf + 32);
        }
        short8 pa0 = *(const short8*)(&sP[l15 * PPAD + kt * TK + quad * 8]);
        short8 pa1 = *(const short8*)(&sP[l15 * PPAD + kt * TK + 32 + quad * 8]);
        oacc = __builtin_amdgcn_mfma_f32_16x16x32_bf16(pa0, vbuf[kt & 3][0], oacc, 0, 0, 0);
        oacc = __builtin_amdgcn_mfma_f32_16x16x32_bf16(pa1, vbuf[kt & 3][1], oacc, 0, 0, 0);
    }

    // ---- epilogue: renormalize + store ----
    float* Ob = O + ((size_t)bh * S_LEN + qt * TQ) * D_DIM;
    const int n0 = wave * 16;
    #pragma unroll
    for (int i = 0; i < 4; ++i) {
        const int row = quad * 4 + i;
        Ob[row * D_DIM + n0 + l15] = oacc[i] * sInv[row];
    }
}

extern "C" void kernel_launch(void* const* d_in, const int* in_sizes, int n_in,
                              void* d_out, int out_size, void* d_ws, size_t ws_size,
                              hipStream_t stream) {
    const float* q = (const float*)d_in[0];
    const float* k = (const float*)d_in[1];
    const float* v = (const float*)d_in[2];
    float* o = (float*)d_out;

    unsigned short* kbf = (unsigned short*)d_ws;                    // 8 MB
    unsigned short* vt  = kbf + (size_t)64 * S_LEN * D_DIM;         // 8 MB

    // merged prepass: 64 bh x 16 s-tiles, K convert + V transpose per block
    prep_kv<<<1024, 256, 0, stream>>>(k, v, kbf, vt);
    // main: 64 bh x 64 q-tiles, XCD-swizzled
    entmax_attn_mfma<<<4096, 256, 0, stream>>>(q, kbf, vt, o);
}